// Round 6
// baseline (1008.478 us; speedup 1.0000x reference)
//
#include <hip/hip_runtime.h>
#include <hip/hip_bf16.h>

// VQ-VAE forward. R13: (1) G1 epilogue emits h PRE-SPLIT (exact 2-term fp16
// split) -> G2 becomes pure pre-split GEMM (no in-loop cvt VALU), BM=64 for
// 2 blocks/CU; h HBM traffic halved. (2) Decoder GEMMs rebuilt on
// global_load_lds staging with add-swizzled LDS chunks (old path: VGPR
// round-trip + 8-way LDS read conflicts). (3) zq gathered as bf16 directly.
// Score/argmin: N-loop fp16 sweeps + exact f64 refine (R12). G1: pre-split
// 3-pass fp16 GEMM (R11).
// Outputs (flat fp32): recon[16384*1024], loss[1], indices-as-float[16384].

#define B_    16384
#define INDIM 1024
#define HID   2048
#define KCB   8192
#define DDIM  128

#define CAND_CAP 2000000u
#define LBUF_CAP 1024u

typedef __bf16    bf16x8   __attribute__((ext_vector_type(8)));
typedef float     floatx4  __attribute__((ext_vector_type(4)));
typedef double    doublex4 __attribute__((ext_vector_type(4)));
typedef _Float16  half8    __attribute__((ext_vector_type(8)));
typedef __fp16    fp16x2   __attribute__((ext_vector_type(2)));

// split scales (exact powers of two)
#define XS 4096.0f              // 2^12 on A (x or h)
#define WS 8192.0f              // 2^13 on W
#define SCALE_INV 2.9802322387695312e-08  // 2^-25

__device__ __forceinline__ unsigned long long pack_key(float d, int code)
{
    unsigned int u = __float_as_uint(d);
    u = (u & 0x80000000u) ? ~u : (u | 0x80000000u);   // total order matching float <
    return ((unsigned long long)u << 32) | (unsigned int)code;
}

__device__ __forceinline__ float unpack_d(unsigned long long key)
{
    unsigned int u = (unsigned int)(key >> 32);
    u = (u & 0x80000000u) ? (u ^ 0x80000000u) : ~u;
    return __uint_as_float(u);
}

// Async global->LDS, 16 B per lane. LDS dest: wave-uniform base + lane*16.
__device__ __forceinline__ void gll16(const float* g, float* l)
{
    __builtin_amdgcn_global_load_lds(
        (const __attribute__((address_space(1))) void*)g,
        (__attribute__((address_space(3))) void*)l, 16, 0, 0);
}

// ---------------------------------------------------------------------------
// Split-fp16 GEMM, A fp32 with IN-REGISTER split (fallback path only).
// ---------------------------------------------------------------------------
template <int ACT, int PMASK>
__launch_bounds__(256)
__global__ void gemm_split_f16(const float* __restrict__ A, const _Float16* __restrict__ Bs_g,
                               const float* __restrict__ bias, float* __restrict__ Cout,
                               int M, int N, int K)
{
    __shared__ float    As[128 * 32];
    __shared__ _Float16 Bsh[64 * 64];

    const int t    = threadIdx.x;
    const int m0   = blockIdx.y * 128, n0 = blockIdx.x * 64;
    const int wave = t >> 6, lane = t & 63;
    const int wr   = (wave >> 1) * 64, wc = (wave & 1) * 32;
    const int quad = lane >> 4, l16 = lane & 15;
    const int lr   = lane >> 3;
    const int lcA  = ((lane & 7) ^ lr) * 4;
    const int slB  = lane & 7;
    const int lrB  = lane >> 3;

    floatx4  accf[4][2];
    doublex4 accd[4][2];
#pragma unroll
    for (int i = 0; i < 4; ++i)
#pragma unroll
        for (int j = 0; j < 2; ++j) {
            accf[i][j] = (floatx4){0.f, 0.f, 0.f, 0.f};
            accd[i][j] = (doublex4){0.0, 0.0, 0.0, 0.0};
        }

    const int NKT = K >> 5;
    for (int kt = 0; kt < NKT; ++kt) {
        const int k0 = kt << 5;
        __syncthreads();
#pragma unroll
        for (int s = 0; s < 4; ++s) {
            int r = wave * 32 + s * 8;
            gll16(A + (size_t)(m0 + r + lr) * K + k0 + lcA, &As[r * 32]);
        }
#pragma unroll
        for (int s = 0; s < 2; ++s) {
            int rb = wave * 16 + s * 8 + lrB;
            int ccs = slB ^ (lrB & 7);
            gll16((const float*)(Bs_g + (size_t)(n0 + rb) * (2 * K) + kt * 64 + ccs * 8),
                  (float*)&Bsh[(wave * 16 + s * 8) * 64]);
        }
        __syncthreads();

        half8 a1[4], a2[4];
#pragma unroll
        for (int i = 0; i < 4; ++i) {
            const int row = wr + i * 16 + l16;
            const int s0  = (2 * quad) ^ (row & 7);
            const int s1  = (2 * quad + 1) ^ (row & 7);
            floatx4 f0 = *(const floatx4*)&As[row * 32 + s0 * 4];
            floatx4 f1 = *(const floatx4*)&As[row * 32 + s1 * 4];
            union { half8 v; fp16x2 h[4]; } u1, u2;
            float sv[8];
#pragma unroll
            for (int q = 0; q < 4; ++q) sv[q] = f0[q] * XS;
#pragma unroll
            for (int q = 0; q < 4; ++q) sv[4 + q] = f1[q] * XS;
#pragma unroll
            for (int q = 0; q < 4; ++q) {
                fp16x2 hi = __builtin_amdgcn_cvt_pkrtz(sv[2 * q], sv[2 * q + 1]);
                u1.h[q] = hi;
                float r0 = sv[2 * q] - (float)hi[0];
                float r1 = sv[2 * q + 1] - (float)hi[1];
                u2.h[q] = __builtin_amdgcn_cvt_pkrtz(r0, r1);
            }
            a1[i] = u1.v; a2[i] = u2.v;
        }
        half8 b1[2], b2[2];
#pragma unroll
        for (int j = 0; j < 2; ++j) {
            const int row = wc + j * 16 + l16;
            b1[j] = *(const half8*)&Bsh[row * 64 + ((0 + quad) ^ (row & 7)) * 8];
            b2[j] = *(const half8*)&Bsh[row * 64 + ((4 + quad) ^ (row & 7)) * 8];
        }
#pragma unroll
        for (int i = 0; i < 4; ++i)
#pragma unroll
            for (int j = 0; j < 2; ++j)
                accf[i][j] = __builtin_amdgcn_mfma_f32_16x16x32_f16(a1[i], b1[j], accf[i][j], 0, 0, 0);
#pragma unroll
        for (int i = 0; i < 4; ++i)
#pragma unroll
            for (int j = 0; j < 2; ++j)
                accf[i][j] = __builtin_amdgcn_mfma_f32_16x16x32_f16(a1[i], b2[j], accf[i][j], 0, 0, 0);
#pragma unroll
        for (int i = 0; i < 4; ++i)
#pragma unroll
            for (int j = 0; j < 2; ++j)
                accf[i][j] = __builtin_amdgcn_mfma_f32_16x16x32_f16(a2[i], b1[j], accf[i][j], 0, 0, 0);

        if ((kt & PMASK) == PMASK) {
#pragma unroll
            for (int i = 0; i < 4; ++i)
#pragma unroll
                for (int j = 0; j < 2; ++j) {
#pragma unroll
                    for (int r = 0; r < 4; ++r)
                        accd[i][j][r] += (double)accf[i][j][r] * SCALE_INV;
                    accf[i][j] = (floatx4){0.f, 0.f, 0.f, 0.f};
                }
        }
    }
    if (NKT & PMASK) {
#pragma unroll
        for (int i = 0; i < 4; ++i)
#pragma unroll
            for (int j = 0; j < 2; ++j)
#pragma unroll
                for (int r = 0; r < 4; ++r)
                    accd[i][j][r] += (double)accf[i][j][r] * SCALE_INV;
    }

#pragma unroll
    for (int i = 0; i < 4; ++i)
#pragma unroll
        for (int j = 0; j < 2; ++j)
#pragma unroll
            for (int r = 0; r < 4; ++r) {
                int row = m0 + wr + i * 16 + quad * 4 + r;
                int col = n0 + wc + j * 16 + l16;
                float f = (float)(accd[i][j][r] + (double)bias[col]);
                if (ACT == 1) f = fmaxf(f, 0.f);
                Cout[(size_t)row * N + col] = f;
            }
}

// ---------------------------------------------------------------------------
// Split-fp16 GEMM, BOTH operands pre-split [rows][2*K] halves.
// IM: i-frag count (BM = IM*32). ACT=1: relu. PMASK: promote period.
// SPLITOUT=1: relu + exact 2-term fp16 split store (h -> hs layout, strides
// 2*N); SPLITOUT=0: fp32 store.
// ---------------------------------------------------------------------------
template <int IM, int ACT, int PMASK, int SPLITOUT>
__launch_bounds__(256)
__global__ void gemm_split_pre(const _Float16* __restrict__ As_g, const _Float16* __restrict__ Bs_g,
                               const float* __restrict__ bias, void* __restrict__ Cp,
                               int M, int N, int K)
{
    __shared__ _Float16 Ash[IM * 32 * 64];
    __shared__ _Float16 Bsh[64 * 64];

    const int t    = threadIdx.x;
    const int m0   = blockIdx.y * (IM * 32), n0 = blockIdx.x * 64;
    const int wave = t >> 6, lane = t & 63;
    const int wr   = (wave >> 1) * (IM * 16), wc = (wave & 1) * 32;
    const int quad = lane >> 4, l16 = lane & 15;
    const int slB  = lane & 7;
    const int lrB  = lane >> 3;
    const int ccs  = slB ^ (lrB & 7);

    floatx4  accf[IM][2];
    doublex4 accd[IM][2];
#pragma unroll
    for (int i = 0; i < IM; ++i)
#pragma unroll
        for (int j = 0; j < 2; ++j) {
            accf[i][j] = (floatx4){0.f, 0.f, 0.f, 0.f};
            accd[i][j] = (doublex4){0.0, 0.0, 0.0, 0.0};
        }

    const int NKT = K >> 5;
    for (int kt = 0; kt < NKT; ++kt) {
        __syncthreads();
#pragma unroll
        for (int s = 0; s < IM; ++s) {
            int ra = wave * (IM * 8) + s * 8 + lrB;
            gll16((const float*)(As_g + (size_t)(m0 + ra) * (2 * K) + kt * 64 + ccs * 8),
                  (float*)&Ash[(wave * (IM * 8) + s * 8) * 64]);
        }
#pragma unroll
        for (int s = 0; s < 2; ++s) {
            int rb = wave * 16 + s * 8 + lrB;
            gll16((const float*)(Bs_g + (size_t)(n0 + rb) * (2 * K) + kt * 64 + ccs * 8),
                  (float*)&Bsh[(wave * 16 + s * 8) * 64]);
        }
        __syncthreads();

        half8 a1[IM], a2[IM], b1[2], b2[2];
#pragma unroll
        for (int i = 0; i < IM; ++i) {
            const int row = wr + i * 16 + l16;
            a1[i] = *(const half8*)&Ash[row * 64 + ((0 + quad) ^ (row & 7)) * 8];
            a2[i] = *(const half8*)&Ash[row * 64 + ((4 + quad) ^ (row & 7)) * 8];
        }
#pragma unroll
        for (int j = 0; j < 2; ++j) {
            const int row = wc + j * 16 + l16;
            b1[j] = *(const half8*)&Bsh[row * 64 + ((0 + quad) ^ (row & 7)) * 8];
            b2[j] = *(const half8*)&Bsh[row * 64 + ((4 + quad) ^ (row & 7)) * 8];
        }
#pragma unroll
        for (int i = 0; i < IM; ++i)
#pragma unroll
            for (int j = 0; j < 2; ++j)
                accf[i][j] = __builtin_amdgcn_mfma_f32_16x16x32_f16(a1[i], b1[j], accf[i][j], 0, 0, 0);
#pragma unroll
        for (int i = 0; i < IM; ++i)
#pragma unroll
            for (int j = 0; j < 2; ++j)
                accf[i][j] = __builtin_amdgcn_mfma_f32_16x16x32_f16(a1[i], b2[j], accf[i][j], 0, 0, 0);
#pragma unroll
        for (int i = 0; i < IM; ++i)
#pragma unroll
            for (int j = 0; j < 2; ++j)
                accf[i][j] = __builtin_amdgcn_mfma_f32_16x16x32_f16(a2[i], b1[j], accf[i][j], 0, 0, 0);

        if ((kt & PMASK) == PMASK) {
#pragma unroll
            for (int i = 0; i < IM; ++i)
#pragma unroll
                for (int j = 0; j < 2; ++j) {
#pragma unroll
                    for (int r = 0; r < 4; ++r)
                        accd[i][j][r] += (double)accf[i][j][r] * SCALE_INV;
                    accf[i][j] = (floatx4){0.f, 0.f, 0.f, 0.f};
                }
        }
    }
    if (NKT & PMASK) {
#pragma unroll
        for (int i = 0; i < IM; ++i)
#pragma unroll
            for (int j = 0; j < 2; ++j)
#pragma unroll
                for (int r = 0; r < 4; ++r)
                    accd[i][j][r] += (double)accf[i][j][r] * SCALE_INV;
    }

#pragma unroll
    for (int i = 0; i < IM; ++i)
#pragma unroll
        for (int j = 0; j < 2; ++j)
#pragma unroll
            for (int r = 0; r < 4; ++r) {
                int row = m0 + wr + i * 16 + quad * 4 + r;
                int col = n0 + wc + j * 16 + l16;
                float f = (float)(accd[i][j][r] + (double)bias[col]);
                if (ACT == 1) f = fmaxf(f, 0.f);
                if (SPLITOUT) {
                    // exact 2-term fp16 split of f*XS, blocked [row][2K] layout
                    float sv = f * XS;
                    _Float16 p0 = (_Float16)sv;
                    _Float16 p1 = (_Float16)(sv - (float)p0);
                    _Float16* hs = (_Float16*)Cp;
                    size_t base = (size_t)row * (2 * (size_t)N)
                                + (size_t)(col >> 5) * 64 + (col & 31);
                    hs[base]      = p0;
                    hs[base + 32] = p1;
                } else {
                    ((float*)Cp)[(size_t)row * N + col] = f;
                }
            }
}

// ---------------------------------------------------------------------------
// bf16 GEMM with gll16 staging + add-swizzled LDS chunks (decoder).
// BM=BN=128, BK=32, 4 waves 2x2 (wave tile 64x64). Row = 32 bf16 = 4 x 16B
// chunks; chunk c stored at slot (c + (row>>1)) & 3  -> 2-way read aliasing.
// ACT=1: relu -> bf16 out. ACT=2: sigmoid -> fp32 out.
// ---------------------------------------------------------------------------
template <int ACT>
__launch_bounds__(256)
__global__ void gemm_bf16_gll(const __bf16* __restrict__ A, const __bf16* __restrict__ BT,
                              const float* __restrict__ bias, void* __restrict__ Cp,
                              int M, int N, int K)
{
    __shared__ __bf16 Asm[128 * 32];
    __shared__ __bf16 Bsm[128 * 32];

    const int t    = threadIdx.x;
    const int m0   = blockIdx.y * 128, n0 = blockIdx.x * 128;
    const int wave = t >> 6, lane = t & 63;
    const int wr   = (wave >> 1) * 64, wc = (wave & 1) * 64;
    const int quad = lane >> 4, l16 = lane & 15;
    const int srow = lane >> 2;          // row within 16-row staging group
    const int schk = lane & 3;           // dest chunk slot

    floatx4 acc[4][4];
#pragma unroll
    for (int i = 0; i < 4; ++i)
#pragma unroll
        for (int j = 0; j < 4; ++j) acc[i][j] = (floatx4){0.f, 0.f, 0.f, 0.f};

    for (int k0 = 0; k0 < K; k0 += 32) {
        __syncthreads();
#pragma unroll
        for (int s = 0; s < 2; ++s) {        // A: wave covers 32 rows
            const int rbase = wave * 32 + s * 16;
            const int ra = rbase + srow;
            const int cs = (schk - (ra >> 1)) & 3;   // inverse add-swizzle
            gll16((const float*)(A + (size_t)(m0 + ra) * K + k0 + cs * 8),
                  (float*)&Asm[rbase * 32]);
        }
#pragma unroll
        for (int s = 0; s < 2; ++s) {        // B: wave covers 32 rows
            const int rbase = wave * 32 + s * 16;
            const int rb = rbase + srow;
            const int cs = (schk - (rb >> 1)) & 3;
            gll16((const float*)(BT + (size_t)(n0 + rb) * K + k0 + cs * 8),
                  (float*)&Bsm[rbase * 32]);
        }
        __syncthreads();

        bf16x8 af[4], bfr[4];
#pragma unroll
        for (int i = 0; i < 4; ++i) {
            const int rl = wr + i * 16 + l16;
            const int sl = (quad + (rl >> 1)) & 3;
            af[i] = *(const bf16x8*)&Asm[rl * 32 + sl * 8];
        }
#pragma unroll
        for (int j = 0; j < 4; ++j) {
            const int rl = wc + j * 16 + l16;
            const int sl = (quad + (rl >> 1)) & 3;
            bfr[j] = *(const bf16x8*)&Bsm[rl * 32 + sl * 8];
        }
#pragma unroll
        for (int i = 0; i < 4; ++i)
#pragma unroll
            for (int j = 0; j < 4; ++j)
                acc[i][j] = __builtin_amdgcn_mfma_f32_16x16x32_bf16(af[i], bfr[j], acc[i][j], 0, 0, 0);
    }

#pragma unroll
    for (int i = 0; i < 4; ++i)
#pragma unroll
        for (int j = 0; j < 4; ++j) {
            int col = n0 + wc + j * 16 + l16;
            float b = bias[col];
#pragma unroll
            for (int r = 0; r < 4; ++r) {
                int row = m0 + wr + i * 16 + quad * 4 + r;
                float v = acc[i][j][r] + b;
                if (ACT == 1) {
                    v = fmaxf(v, 0.f);
                    ((__bf16*)Cp)[(size_t)row * N + col] = (__bf16)v;
                } else {
                    v = 1.f / (1.f + __expf(-v));
                    ((float*)Cp)[(size_t)row * N + col] = v;
                }
            }
        }
}

// x [M][K] fp32 -> xs [M][2K] halves, blocked [ktile][plane][kchunk][8].
__global__ void split_x(const float* __restrict__ in, _Float16* __restrict__ outS, int n8)
{
    int i = blockIdx.x * 256 + threadIdx.x;
    if (i >= n8) return;
    const int K = INDIM;
    int m  = i / (K / 8);
    int k8 = i % (K / 8);
    int k  = k8 * 8;
    const float* src = in + (size_t)m * K + k;
    floatx4 f0 = *(const floatx4*)(src);
    floatx4 f1 = *(const floatx4*)(src + 4);
    union { half8 v; fp16x2 h[4]; } u1, u2;
    float sv[8];
#pragma unroll
    for (int q = 0; q < 4; ++q) sv[q] = f0[q] * XS;
#pragma unroll
    for (int q = 0; q < 4; ++q) sv[4 + q] = f1[q] * XS;
#pragma unroll
    for (int q = 0; q < 4; ++q) {
        fp16x2 hi = __builtin_amdgcn_cvt_pkrtz(sv[2 * q], sv[2 * q + 1]);
        u1.h[q] = hi;
        float r0 = sv[2 * q] - (float)hi[0];
        float r1 = sv[2 * q + 1] - (float)hi[1];
        u2.h[q] = __builtin_amdgcn_cvt_pkrtz(r0, r1);
    }
    size_t base = (size_t)m * (2 * K) + (size_t)(k >> 5) * 64 + (k & 31);
    *(half8*)(outS + base)      = u1.v;     // plane 0
    *(half8*)(outS + base + 32) = u2.v;     // plane 1
}

// W [K][N] fp32 -> [N][2K] halves (same blocked layout), transposed.
__global__ void transpose_split_f16(const float* __restrict__ in, _Float16* __restrict__ outS,
                                    int K, int N)
{
    __shared__ float tile[32][33];
    int k0 = blockIdx.x * 32, n0 = blockIdx.y * 32;
    int tr = threadIdx.x >> 5, tc = threadIdx.x & 31;
#pragma unroll
    for (int s = 0; s < 4; ++s)
        tile[tr + 8 * s][tc] = in[(size_t)(k0 + tr + 8 * s) * N + n0 + tc];
    __syncthreads();
#pragma unroll
    for (int s = 0; s < 4; ++s) {
        int n = n0 + tr + 8 * s;
        int k = k0 + tc;
        float w = tile[tc][tr + 8 * s] * WS;
        _Float16 p0 = (_Float16)w;
        float r = w - (float)p0;
        _Float16 p1 = (_Float16)r;
        size_t base = (size_t)n * (2 * K) + (size_t)(k >> 5) * 64 + (k & 31);
        outS[base]      = p0;
        outS[base + 32] = p1;
    }
}

// ---------------------------------------------------------------------------
// rownorm32[k] = fl32( sum_fp64( fl32(row[k][d]^2) ) ). One wave per row.
// ---------------------------------------------------------------------------
__global__ void rownorm_kernel(const float* __restrict__ M, float* __restrict__ nrm)
{
    int k = blockIdx.x * 4 + (threadIdx.x >> 6);
    int lane = threadIdx.x & 63;
    float2 c = *(const float2*)(M + (size_t)k * DDIM + lane * 2);
    float q0 = c.x * c.x;
    float q1 = c.y * c.y;
    double s = (double)q0 + (double)q1;
#pragma unroll
    for (int off = 32; off > 0; off >>= 1) s += __shfl_down(s, off);
    if (lane == 0) nrm[k] = (float)s;
}

// max over cn32 (one block).
__global__ void cnmax_kernel(const float* __restrict__ cn, float* __restrict__ out)
{
    __shared__ float red[4];
    int t = threadIdx.x;
    float m = 0.f;
    for (int i = t; i < KCB; i += 256) m = fmaxf(m, cn[i]);
#pragma unroll
    for (int off = 32; off > 0; off >>= 1) m = fmaxf(m, __shfl_down(m, off));
    if ((t & 63) == 0) red[t >> 6] = m;
    __syncthreads();
    if (t == 0) out[0] = fmaxf(fmaxf(red[0], red[1]), fmaxf(red[2], red[3]));
}

// fp32 -> fp16 (optionally scaled by an exact power of two), 8 elems/thread.
__global__ void cvt_half(const float* __restrict__ in, _Float16* __restrict__ out,
                         float scale, int n8)
{
    int i = blockIdx.x * 256 + threadIdx.x;
    if (i >= n8) return;
    const float4 a = *(const float4*)(in + (size_t)i * 8);
    const float4 b = *(const float4*)(in + (size_t)i * 8 + 4);
    half8 h;
    h[0] = (_Float16)(a.x * scale); h[1] = (_Float16)(a.y * scale);
    h[2] = (_Float16)(a.z * scale); h[3] = (_Float16)(a.w * scale);
    h[4] = (_Float16)(b.x * scale); h[5] = (_Float16)(b.y * scale);
    h[6] = (_Float16)(b.z * scale); h[7] = (_Float16)(b.w * scale);
    *(half8*)(out + (size_t)i * 8) = h;
}

// ---------------------------------------------------------------------------
// R12 N-loop score sweeps (proven). Block = 32 z-rows x ALL 8192 codes.
// ---------------------------------------------------------------------------
template <int EMIT>
__launch_bounds__(256)
__global__ void score_sweep2(const _Float16* __restrict__ zh, const _Float16* __restrict__ ch,
                             const float* __restrict__ nz32, const float* __restrict__ cn32,
                             unsigned long long* __restrict__ gbestA,
                             const float* __restrict__ cnmaxp,
                             unsigned* __restrict__ listCnt, unsigned* __restrict__ list)
{
    __shared__ __align__(16) _Float16 Zs[32 * 128];    //  8 KB
    __shared__ __align__(16) _Float16 Cs[128 * 128];   // 32 KB
    __shared__ unsigned long long best[32];            // EMIT==0 combine
    __shared__ unsigned lbuf[LBUF_CAP];                // EMIT==1 candidates
    __shared__ unsigned lcnt, lbase;

    const int t    = threadIdx.x;
    const int m0   = blockIdx.x * 32;
    const int wave = t >> 6, lane = t & 63;
    const int quad = lane >> 4, l16 = lane & 15;
    const int srow = lane >> 4, sc = lane & 15;

    if (EMIT == 0) { if (t < 32) best[t] = ~0ull; }
    else if (t == 0) lcnt = 0u;

#pragma unroll
    for (int s = 0; s < 2; ++s) {
        const int rbase = s * 16 + wave * 4;
        const int ra = rbase + srow;
        const int cs = sc ^ ((ra & 7) << 1);
        gll16((const float*)(zh + (size_t)(m0 + ra) * 128 + cs * 8),
              (float*)&Zs[rbase * 128]);
    }
    __syncthreads();

    half8 af[2][4];
#pragma unroll
    for (int i = 0; i < 2; ++i) {
        const int rl = i * 16 + l16;
#pragma unroll
        for (int ks = 0; ks < 4; ++ks) {
            const int cc = (ks * 4 + quad) ^ ((rl & 7) << 1);
            af[i][ks] = *(const half8*)&Zs[rl * 128 + cc * 8];
        }
    }

    const float cnm = *cnmaxp;
    float nzv[8], thr[8], bd[8];
    int   bc[8];
#pragma unroll
    for (int i = 0; i < 2; ++i)
#pragma unroll
        for (int r = 0; r < 4; ++r) {
            const int q = i * 4 + r;
            const int grow = m0 + i * 16 + quad * 4 + r;
            nzv[q] = nz32[grow];
            if (EMIT) {
                thr[q] = unpack_d(gbestA[grow]) + 2.4e-3f * sqrtf(nzv[q] * cnm) + 6.0e-5f;
            } else {
                bd[q] = 3.4e38f; bc[q] = 0x7fffffff;
            }
        }

    for (int nt = 0; nt < KCB / 128; ++nt) {
        const int n0 = nt * 128;
        __syncthreads();
#pragma unroll
        for (int s = 0; s < 8; ++s) {
            const int rbase = s * 16 + wave * 4;
            const int ra = rbase + srow;
            const int cs = sc ^ ((ra & 7) << 1);
            gll16((const float*)(ch + (size_t)(n0 + ra) * 128 + cs * 8),
                  (float*)&Cs[rbase * 128]);
        }
        __syncthreads();

        floatx4 acc[2][2];
#pragma unroll
        for (int i = 0; i < 2; ++i)
#pragma unroll
            for (int j = 0; j < 2; ++j) acc[i][j] = (floatx4){0.f, 0.f, 0.f, 0.f};
#pragma unroll
        for (int ks = 0; ks < 4; ++ks) {
            half8 bf[2];
#pragma unroll
            for (int j = 0; j < 2; ++j) {
                const int rl = wave * 32 + j * 16 + l16;
                const int cc = (ks * 4 + quad) ^ ((rl & 7) << 1);
                bf[j] = *(const half8*)&Cs[rl * 128 + cc * 8];
            }
#pragma unroll
            for (int i = 0; i < 2; ++i)
#pragma unroll
                for (int j = 0; j < 2; ++j)
                    acc[i][j] = __builtin_amdgcn_mfma_f32_16x16x32_f16(af[i][ks], bf[j], acc[i][j], 0, 0, 0);
        }

#pragma unroll
        for (int i = 0; i < 2; ++i)
#pragma unroll
            for (int r = 0; r < 4; ++r) {
                const int q = i * 4 + r;
#pragma unroll
                for (int j = 0; j < 2; ++j) {
                    const int code = n0 + wave * 32 + j * 16 + l16;
                    float s = acc[i][j][r] * (1.0f / 4096.0f);
                    float d = (nzv[q] - 2.0f * s) + cn32[code];
                    if (EMIT) {
                        if (d <= thr[q]) {
                            unsigned ent = ((unsigned)(m0 + i * 16 + quad * 4 + r) << 13) | (unsigned)code;
                            unsigned idx = atomicAdd(&lcnt, 1u);
                            if (idx < LBUF_CAP) lbuf[idx] = ent;
                            else {
                                unsigned g = atomicAdd(listCnt, 1u);
                                if (g < CAND_CAP) list[g] = ent;
                            }
                        }
                    } else {
                        if (d < bd[q]) { bd[q] = d; bc[q] = code; }
                    }
                }
            }
    }

    if (EMIT == 0) {
#pragma unroll
        for (int i = 0; i < 2; ++i)
#pragma unroll
            for (int r = 0; r < 4; ++r) {
                const int q = i * 4 + r;
                atomicMin(&best[i * 16 + quad * 4 + r], pack_key(bd[q], bc[q]));
            }
        __syncthreads();
        if (t < 32) gbestA[m0 + t] = best[t];
    } else {
        __syncthreads();
        unsigned cnt = lcnt; if (cnt > LBUF_CAP) cnt = LBUF_CAP;
        if (t == 0) lbase = atomicAdd(listCnt, cnt);
        __syncthreads();
        for (unsigned e = t; e < cnt; e += 256) {
            unsigned g = lbase + e;
            if (g < CAND_CAP) list[g] = lbuf[e];
        }
    }
}

// Exact refine: one wave per candidate pair.
__launch_bounds__(256)
__global__ void refine_kernel(const float* __restrict__ z, const float* __restrict__ cb,
                              const float* __restrict__ nz32, const float* __restrict__ cn32,
                              const unsigned* __restrict__ listCnt,
                              const unsigned* __restrict__ list,
                              unsigned long long* __restrict__ gbest)
{
    unsigned cnt = *listCnt;
    if (cnt > CAND_CAP) cnt = CAND_CAP;
    const int lane = threadIdx.x & 63;
    for (unsigned p = blockIdx.x * 4 + (threadIdx.x >> 6); p < cnt; p += gridDim.x * 4) {
        const unsigned e = list[p];
        const int r = (int)(e >> 13), k = (int)(e & 8191u);
        float2 zv = *(const float2*)(z  + (size_t)r * DDIM + lane * 2);
        float2 cv = *(const float2*)(cb + (size_t)k * DDIM + lane * 2);
        double s = (double)zv.x * (double)cv.x + (double)zv.y * (double)cv.y;
#pragma unroll
        for (int off = 32; off > 0; off >>= 1) s += __shfl_down(s, off);
        if (lane == 0) {
            float s32 = (float)s;
            float d = (nz32[r] - 2.0f * s32) + cn32[k];
            atomicMin(&gbest[r], pack_key(d, k));
        }
    }
}

__global__ void init_gbest(unsigned long long* __restrict__ g)
{
    g[blockIdx.x * 256 + threadIdx.x] = ~0ull;
}

// Gather z_q = codebook[idx] as bf16 (zqb) + accumulate sum((z_q - z)^2) f64.
__global__ void gather_zq_loss(const float* __restrict__ z, const float* __restrict__ cb,
                               const unsigned long long* __restrict__ gbest,
                               __bf16* __restrict__ zqb, double* __restrict__ acc)
{
    int r = blockIdx.x * 4 + (threadIdx.x >> 6);
    int lane = threadIdx.x & 63;
    int k = (int)(gbest[r] & 0xffffffffull);
    float2 zv = *(const float2*)(z  + (size_t)r * DDIM + lane * 2);
    float2 cv = *(const float2*)(cb + (size_t)k * DDIM + lane * 2);
    __bf16 b0 = (__bf16)cv.x, b1 = (__bf16)cv.y;
    zqb[(size_t)r * DDIM + lane * 2]     = b0;
    zqb[(size_t)r * DDIM + lane * 2 + 1] = b1;
    double dx = (double)cv.x - (double)zv.x, dy = (double)cv.y - (double)zv.y;
    double s = dx * dx + dy * dy;
#pragma unroll
    for (int off = 32; off > 0; off >>= 1) s += __shfl_down(s, off);
    if (lane == 0) atomicAdd(acc, s);
}

__global__ void init_scalars(double* acc, unsigned* cnt)
{
    if (threadIdx.x == 0 && blockIdx.x == 0) { *acc = 0.0; *cnt = 0u; }
}

__global__ void finalize_kernel(const unsigned long long* __restrict__ gbest,
                                const double* __restrict__ acc, float* __restrict__ out)
{
    int tid = blockIdx.x * 256 + threadIdx.x;
    if (tid < B_) out[16777217 + tid] = (float)(int)(gbest[tid] & 0xffffffffull);
    if (tid == 0) out[16777216] = (float)((*acc) * 1.25 / (double)(B_ * DDIM));
}

// ---------------------------------------------------------------------------
// One-time weight transposes: fp32 [K][N] -> bf16 [N][K].
// ---------------------------------------------------------------------------
__global__ void transpose_to_bf16(const float* __restrict__ in, __bf16* __restrict__ outT,
                                  int K, int N)
{
    __shared__ float tile[32][33];
    int k0 = blockIdx.x * 32, n0 = blockIdx.y * 32;
    int tr = threadIdx.x >> 5, tc = threadIdx.x & 31;
#pragma unroll
    for (int s = 0; s < 4; ++s)
        tile[tr + 8 * s][tc] = in[(size_t)(k0 + tr + 8 * s) * N + n0 + tc];
    __syncthreads();
#pragma unroll
    for (int s = 0; s < 4; ++s)
        outT[(size_t)(n0 + tr + 8 * s) * K + k0 + tc] = (__bf16)tile[tc][tr + 8 * s];
}

// ---------------------------------------------------------------------------
extern "C" void kernel_launch(void* const* d_in, const int* in_sizes, int n_in,
                              void* d_out, int out_size, void* d_ws, size_t ws_size,
                              hipStream_t stream)
{
    const float* x  = (const float*)d_in[0];
    const float* W1 = (const float*)d_in[1];
    const float* b1 = (const float*)d_in[2];
    const float* W2 = (const float*)d_in[3];
    const float* b2 = (const float*)d_in[4];
    const float* cb = (const float*)d_in[5];
    const float* W3 = (const float*)d_in[6];
    const float* b3 = (const float*)d_in[7];
    const float* W4 = (const float*)d_in[8];
    const float* b4 = (const float*)d_in[9];
    float* out = (float*)d_out;

    char* ws = (char*)d_ws;
    // hs split-h (64MB) at ws+0, live G1->G2; fallback h fp32 same region.
    // h2b (decoder) at +16MB written post-G2. Dead-hs region [0,16MB) hosts
    // post-G2 score scratch (zh/ch/gbestA/list).
    _Float16* hs = (_Float16*)(ws);                   // 64 MB [16384][2*2048]
    float*  h    = (float*)(ws);                      // fallback fp32
    __bf16* h2b  = (__bf16*)(ws + 16777216ull);       // 64 MB
    float*  z32  = (float*)(ws + 134217728ull);       //  8 MB
    __bf16* zqb  = (__bf16*)(ws + 142606336ull);      //  4 MB (in zq slot)
    _Float16* W1s = (_Float16*)(ws + 142606336ull);   //  8 MB (alias of zqb; dead before gather)
    float*  nz32 = (float*)(ws + 150994944ull);       // 64 KB
    float*  cn32 = (float*)(ws + 151060480ull);       // 32 KB
    unsigned long long* gbest = (unsigned long long*)(ws + 151093248ull); // 128 KB
    double* acc  = (double*)(ws + 151224320ull);      // 8 B (4KB pad)
    float*  cnmax   = (float*)(ws + 151224328ull);    // 4 B
    unsigned* listCnt = (unsigned*)(ws + 151224332ull); // 4 B
    __bf16* W3t  = (__bf16*)(ws + 151228416ull);      // 512 KB [2048][128]
    __bf16* W4t  = (__bf16*)(ws + 151752704ull);      //   4 MB [1024][2048]
    _Float16* W2s = (_Float16*)(ws + 155947008ull);   //   1 MB [128][2*2048]

    _Float16* zh  = (_Float16*)(ws);                  // dead-hs region (post-G2)
    _Float16* chh = (_Float16*)(ws + 4194304ull);
    unsigned long long* gbestA = (unsigned long long*)(ws + 6291456ull);
    unsigned* list = (unsigned*)(ws + 8388608ull);

    const unsigned long long XS_OFF = 157286400ull;   // 150 MB
    _Float16* xs = (_Float16*)(ws + XS_OFF);
    const bool pre_split_x = (ws_size >= XS_OFF + 67108864ull);

    init_scalars<<<1, 64, 0, stream>>>(acc, listCnt);
    init_gbest<<<B_ / 256, 256, 0, stream>>>(gbest);
    rownorm_kernel<<<KCB / 4, 256, 0, stream>>>(cb, cn32);
    cnmax_kernel<<<1, 256, 0, stream>>>(cn32, cnmax);
    transpose_to_bf16<<<dim3(DDIM / 32, HID / 32), 256, 0, stream>>>(W3, W3t, DDIM, HID);
    transpose_to_bf16<<<dim3(HID / 32, INDIM / 32), 256, 0, stream>>>(W4, W4t, HID, INDIM);
    transpose_split_f16<<<dim3(INDIM / 32, HID / 32), 256, 0, stream>>>(W1, W1s, INDIM, HID);
    transpose_split_f16<<<dim3(HID / 32, DDIM / 32), 256, 0, stream>>>(W2, W2s, HID, DDIM);

    if (pre_split_x) {
        // h(split) = relu(x@W1 + b1): pre-split GEMM, split-store epilogue
        split_x<<<(B_ * INDIM / 8) / 256, 256, 0, stream>>>(x, xs, B_ * INDIM / 8);
        gemm_split_pre<4, 1, 3, 1><<<dim3(HID / 64, B_ / 128), 256, 0, stream>>>(
            xs, W1s, b1, (void*)hs, B_, HID, INDIM);
        // z32 = h@W2 + b2: pure pre-split GEMM, BM=64 (grid 512 = 2/CU)
        gemm_split_pre<2, 0, 1, 0><<<dim3(DDIM / 64, B_ / 64), 256, 0, stream>>>(
            hs, W2s, b2, (void*)z32, B_, DDIM, HID);
    } else {
        gemm_split_f16<1, 3><<<dim3(HID / 64, B_ / 128), 256, 0, stream>>>(
            x, W1s, b1, h, B_, HID, INDIM);
        gemm_split_f16<0, 1><<<dim3(DDIM / 64, B_ / 128), 256, 0, stream>>>(
            h, W2s, b2, z32, B_, DDIM, HID);
    }
    // nz32 = fl32(sum fl32(z^2))
    rownorm_kernel<<<B_ / 4, 256, 0, stream>>>(z32, nz32);

    // --- fast score path: N-loop fp16 sweeps + exact refine ---
    cvt_half<<<(B_ * DDIM / 8) / 256, 256, 0, stream>>>(z32, zh, 1.0f, B_ * DDIM / 8);
    cvt_half<<<(KCB * DDIM / 8) / 256, 256, 0, stream>>>(cb, chh, 4096.0f, KCB * DDIM / 8);
    score_sweep2<0><<<B_ / 32, 256, 0, stream>>>(
        zh, chh, nz32, cn32, gbestA, cnmax, listCnt, list);
    score_sweep2<1><<<B_ / 32, 256, 0, stream>>>(
        zh, chh, nz32, cn32, gbestA, cnmax, listCnt, list);
    refine_kernel<<<1024, 256, 0, stream>>>(z32, cb, nz32, cn32, listCnt, list, gbest);

    // z_q gather (bf16) + commitment loss
    gather_zq_loss<<<B_ / 4, 256, 0, stream>>>(z32, cb, gbest, zqb, acc);
    // h2 = relu(zqb@W3 + b3) -> bf16              [16384,128]x[128,2048]
    gemm_bf16_gll<1><<<dim3(HID / 128, B_ / 128), 256, 0, stream>>>(
        zqb, W3t, b3, (void*)h2b, B_, HID, DDIM);
    // recon = sigmoid(h2@W4 + b4) -> fp32 out     [16384,2048]x[2048,1024]
    gemm_bf16_gll<2><<<dim3(INDIM / 128, B_ / 128), 256, 0, stream>>>(
        h2b, W4t, b4, (void*)out, B_, INDIM, HID);

    finalize_kernel<<<B_ / 256, 256, 0, stream>>>(gbest, acc, out);
}

// Round 10
// 925.554 us; speedup vs baseline: 1.0896x; 1.0896x over previous
//
#include <hip/hip_runtime.h>
#include <hip/hip_bf16.h>

// VQ-VAE forward. R17 = R14 with the zh/chh placement bug fixed. R16 failed
// (indices absmax 8084) because zh/chh were placed at +80/+84MB inside hs --
// hs is 128MB ([16384][2*2048] halves), NOT 64MB: chh (preamble) was
// clobbered by G1's hs write; zh (G2 epilogue) raced other blocks' hs reads.
// Fix: zh/chh generated POST-G2 via cvt_half into the then-dead hs region at
// +0/+4MB (R13-proven dataflow). KEPT from R14: bijective XCD swizzle on all
// GEMM grids + sweeps, sweep cn32 hoist (16->2 VMEM/iter), merged init.
// Pipeline: G1 = pre-split 3-pass fp16 GEMM; G2 = pre-split GEMM (h emitted
// split by G1); score = N-loop fp16 sweeps + exact f64 refine; decoder = bf16
// gll GEMMs.
// Outputs (flat fp32): recon[16384*1024], loss[1], indices-as-float[16384].

#define B_    16384
#define INDIM 1024
#define HID   2048
#define KCB   8192
#define DDIM  128

#define CAND_CAP 2000000u
#define LBUF_CAP 1024u

typedef __bf16    bf16x8   __attribute__((ext_vector_type(8)));
typedef float     floatx4  __attribute__((ext_vector_type(4)));
typedef double    doublex4 __attribute__((ext_vector_type(4)));
typedef _Float16  half8    __attribute__((ext_vector_type(8)));
typedef __fp16    fp16x2   __attribute__((ext_vector_type(2)));

// split scales (exact powers of two)
#define XS 4096.0f              // 2^12 on A (x or h)
#define WS 8192.0f              // 2^13 on W
#define SCALE_INV 2.9802322387695312e-08  // 2^-25

__device__ __forceinline__ unsigned long long pack_key(float d, int code)
{
    unsigned int u = __float_as_uint(d);
    u = (u & 0x80000000u) ? ~u : (u | 0x80000000u);   // total order matching float <
    return ((unsigned long long)u << 32) | (unsigned int)code;
}

__device__ __forceinline__ float unpack_d(unsigned long long key)
{
    unsigned int u = (unsigned int)(key >> 32);
    u = (u & 0x80000000u) ? (u ^ 0x80000000u) : ~u;
    return __uint_as_float(u);
}

// Async global->LDS, 16 B per lane. LDS dest: wave-uniform base + lane*16.
__device__ __forceinline__ void gll16(const float* g, float* l)
{
    __builtin_amdgcn_global_load_lds(
        (const __attribute__((address_space(1))) void*)g,
        (__attribute__((address_space(3))) void*)l, 16, 0, 0);
}

// ---------------------------------------------------------------------------
// Split-fp16 GEMM, A fp32 with IN-REGISTER split (fallback path only).
// ---------------------------------------------------------------------------
template <int ACT, int PMASK>
__launch_bounds__(256)
__global__ void gemm_split_f16(const float* __restrict__ A, const _Float16* __restrict__ Bs_g,
                               const float* __restrict__ bias, float* __restrict__ Cout,
                               int M, int N, int K)
{
    __shared__ float    As[128 * 32];
    __shared__ _Float16 Bsh[64 * 64];

    const int t    = threadIdx.x;
    const int m0   = blockIdx.y * 128, n0 = blockIdx.x * 64;
    const int wave = t >> 6, lane = t & 63;
    const int wr   = (wave >> 1) * 64, wc = (wave & 1) * 32;
    const int quad = lane >> 4, l16 = lane & 15;
    const int lr   = lane >> 3;
    const int lcA  = ((lane & 7) ^ lr) * 4;
    const int slB  = lane & 7;
    const int lrB  = lane >> 3;

    floatx4  accf[4][2];
    doublex4 accd[4][2];
#pragma unroll
    for (int i = 0; i < 4; ++i)
#pragma unroll
        for (int j = 0; j < 2; ++j) {
            accf[i][j] = (floatx4){0.f, 0.f, 0.f, 0.f};
            accd[i][j] = (doublex4){0.0, 0.0, 0.0, 0.0};
        }

    const int NKT = K >> 5;
    for (int kt = 0; kt < NKT; ++kt) {
        const int k0 = kt << 5;
        __syncthreads();
#pragma unroll
        for (int s = 0; s < 4; ++s) {
            int r = wave * 32 + s * 8;
            gll16(A + (size_t)(m0 + r + lr) * K + k0 + lcA, &As[r * 32]);
        }
#pragma unroll
        for (int s = 0; s < 2; ++s) {
            int rb = wave * 16 + s * 8 + lrB;
            int ccs = slB ^ (lrB & 7);
            gll16((const float*)(Bs_g + (size_t)(n0 + rb) * (2 * K) + kt * 64 + ccs * 8),
                  (float*)&Bsh[(wave * 16 + s * 8) * 64]);
        }
        __syncthreads();

        half8 a1[4], a2[4];
#pragma unroll
        for (int i = 0; i < 4; ++i) {
            const int row = wr + i * 16 + l16;
            const int s0  = (2 * quad) ^ (row & 7);
            const int s1  = (2 * quad + 1) ^ (row & 7);
            floatx4 f0 = *(const floatx4*)&As[row * 32 + s0 * 4];
            floatx4 f1 = *(const floatx4*)&As[row * 32 + s1 * 4];
            union { half8 v; fp16x2 h[4]; } u1, u2;
            float sv[8];
#pragma unroll
            for (int q = 0; q < 4; ++q) sv[q] = f0[q] * XS;
#pragma unroll
            for (int q = 0; q < 4; ++q) sv[4 + q] = f1[q] * XS;
#pragma unroll
            for (int q = 0; q < 4; ++q) {
                fp16x2 hi = __builtin_amdgcn_cvt_pkrtz(sv[2 * q], sv[2 * q + 1]);
                u1.h[q] = hi;
                float r0 = sv[2 * q] - (float)hi[0];
                float r1 = sv[2 * q + 1] - (float)hi[1];
                u2.h[q] = __builtin_amdgcn_cvt_pkrtz(r0, r1);
            }
            a1[i] = u1.v; a2[i] = u2.v;
        }
        half8 b1[2], b2[2];
#pragma unroll
        for (int j = 0; j < 2; ++j) {
            const int row = wc + j * 16 + l16;
            b1[j] = *(const half8*)&Bsh[row * 64 + ((0 + quad) ^ (row & 7)) * 8];
            b2[j] = *(const half8*)&Bsh[row * 64 + ((4 + quad) ^ (row & 7)) * 8];
        }
#pragma unroll
        for (int i = 0; i < 4; ++i)
#pragma unroll
            for (int j = 0; j < 2; ++j)
                accf[i][j] = __builtin_amdgcn_mfma_f32_16x16x32_f16(a1[i], b1[j], accf[i][j], 0, 0, 0);
#pragma unroll
        for (int i = 0; i < 4; ++i)
#pragma unroll
            for (int j = 0; j < 2; ++j)
                accf[i][j] = __builtin_amdgcn_mfma_f32_16x16x32_f16(a1[i], b2[j], accf[i][j], 0, 0, 0);
#pragma unroll
        for (int i = 0; i < 4; ++i)
#pragma unroll
            for (int j = 0; j < 2; ++j)
                accf[i][j] = __builtin_amdgcn_mfma_f32_16x16x32_f16(a2[i], b1[j], accf[i][j], 0, 0, 0);

        if ((kt & PMASK) == PMASK) {
#pragma unroll
            for (int i = 0; i < 4; ++i)
#pragma unroll
                for (int j = 0; j < 2; ++j) {
#pragma unroll
                    for (int r = 0; r < 4; ++r)
                        accd[i][j][r] += (double)accf[i][j][r] * SCALE_INV;
                    accf[i][j] = (floatx4){0.f, 0.f, 0.f, 0.f};
                }
        }
    }
    if (NKT & PMASK) {
#pragma unroll
        for (int i = 0; i < 4; ++i)
#pragma unroll
            for (int j = 0; j < 2; ++j)
#pragma unroll
                for (int r = 0; r < 4; ++r)
                    accd[i][j][r] += (double)accf[i][j][r] * SCALE_INV;
    }

#pragma unroll
    for (int i = 0; i < 4; ++i)
#pragma unroll
        for (int j = 0; j < 2; ++j)
#pragma unroll
            for (int r = 0; r < 4; ++r) {
                int row = m0 + wr + i * 16 + quad * 4 + r;
                int col = n0 + wc + j * 16 + l16;
                float f = (float)(accd[i][j][r] + (double)bias[col]);
                if (ACT == 1) f = fmaxf(f, 0.f);
                Cout[(size_t)row * N + col] = f;
            }
}

// ---------------------------------------------------------------------------
// Split-fp16 GEMM, BOTH operands pre-split [rows][2*K] halves.
// IM: i-frag count (BM = IM*32). ACT=1: relu. PMASK: promote period.
// SPLITOUT=1: split-store (h -> hs). SPLITOUT=0: fp32 store.
// XCD-swizzled block mapping (nwg % 8 == 0).
// ---------------------------------------------------------------------------
template <int IM, int ACT, int PMASK, int SPLITOUT>
__launch_bounds__(256)
__global__ void gemm_split_pre(const _Float16* __restrict__ As_g, const _Float16* __restrict__ Bs_g,
                               const float* __restrict__ bias, void* __restrict__ Cp,
                               int M, int N, int K)
{
    __shared__ _Float16 Ash[IM * 32 * 64];
    __shared__ _Float16 Bsh[64 * 64];

    const int t    = threadIdx.x;
    const int nwg  = gridDim.x * gridDim.y;
    int lin = blockIdx.y * gridDim.x + blockIdx.x;
    lin = (lin & 7) * (nwg >> 3) + (lin >> 3);        // bijective XCD swizzle
    const int bx = lin % gridDim.x, by = lin / gridDim.x;
    const int m0   = by * (IM * 32), n0 = bx * 64;
    const int wave = t >> 6, lane = t & 63;
    const int wr   = (wave >> 1) * (IM * 16), wc = (wave & 1) * 32;
    const int quad = lane >> 4, l16 = lane & 15;
    const int slB  = lane & 7;
    const int lrB  = lane >> 3;
    const int ccs  = slB ^ (lrB & 7);

    floatx4  accf[IM][2];
    doublex4 accd[IM][2];
#pragma unroll
    for (int i = 0; i < IM; ++i)
#pragma unroll
        for (int j = 0; j < 2; ++j) {
            accf[i][j] = (floatx4){0.f, 0.f, 0.f, 0.f};
            accd[i][j] = (doublex4){0.0, 0.0, 0.0, 0.0};
        }

    const int NKT = K >> 5;
    for (int kt = 0; kt < NKT; ++kt) {
        __syncthreads();
#pragma unroll
        for (int s = 0; s < IM; ++s) {
            int ra = wave * (IM * 8) + s * 8 + lrB;
            gll16((const float*)(As_g + (size_t)(m0 + ra) * (2 * K) + kt * 64 + ccs * 8),
                  (float*)&Ash[(wave * (IM * 8) + s * 8) * 64]);
        }
#pragma unroll
        for (int s = 0; s < 2; ++s) {
            int rb = wave * 16 + s * 8 + lrB;
            gll16((const float*)(Bs_g + (size_t)(n0 + rb) * (2 * K) + kt * 64 + ccs * 8),
                  (float*)&Bsh[(wave * 16 + s * 8) * 64]);
        }
        __syncthreads();

        half8 a1[IM], a2[IM], b1[2], b2[2];
#pragma unroll
        for (int i = 0; i < IM; ++i) {
            const int row = wr + i * 16 + l16;
            a1[i] = *(const half8*)&Ash[row * 64 + ((0 + quad) ^ (row & 7)) * 8];
            a2[i] = *(const half8*)&Ash[row * 64 + ((4 + quad) ^ (row & 7)) * 8];
        }
#pragma unroll
        for (int j = 0; j < 2; ++j) {
            const int row = wc + j * 16 + l16;
            b1[j] = *(const half8*)&Bsh[row * 64 + ((0 + quad) ^ (row & 7)) * 8];
            b2[j] = *(const half8*)&Bsh[row * 64 + ((4 + quad) ^ (row & 7)) * 8];
        }
#pragma unroll
        for (int i = 0; i < IM; ++i)
#pragma unroll
            for (int j = 0; j < 2; ++j)
                accf[i][j] = __builtin_amdgcn_mfma_f32_16x16x32_f16(a1[i], b1[j], accf[i][j], 0, 0, 0);
#pragma unroll
        for (int i = 0; i < IM; ++i)
#pragma unroll
            for (int j = 0; j < 2; ++j)
                accf[i][j] = __builtin_amdgcn_mfma_f32_16x16x32_f16(a1[i], b2[j], accf[i][j], 0, 0, 0);
#pragma unroll
        for (int i = 0; i < IM; ++i)
#pragma unroll
            for (int j = 0; j < 2; ++j)
                accf[i][j] = __builtin_amdgcn_mfma_f32_16x16x32_f16(a2[i], b1[j], accf[i][j], 0, 0, 0);

        if ((kt & PMASK) == PMASK) {
#pragma unroll
            for (int i = 0; i < IM; ++i)
#pragma unroll
                for (int j = 0; j < 2; ++j) {
#pragma unroll
                    for (int r = 0; r < 4; ++r)
                        accd[i][j][r] += (double)accf[i][j][r] * SCALE_INV;
                    accf[i][j] = (floatx4){0.f, 0.f, 0.f, 0.f};
                }
        }
    }
    if (NKT & PMASK) {
#pragma unroll
        for (int i = 0; i < IM; ++i)
#pragma unroll
            for (int j = 0; j < 2; ++j)
#pragma unroll
                for (int r = 0; r < 4; ++r)
                    accd[i][j][r] += (double)accf[i][j][r] * SCALE_INV;
    }

#pragma unroll
    for (int i = 0; i < IM; ++i)
#pragma unroll
        for (int j = 0; j < 2; ++j)
#pragma unroll
            for (int r = 0; r < 4; ++r) {
                int row = m0 + wr + i * 16 + quad * 4 + r;
                int col = n0 + wc + j * 16 + l16;
                float f = (float)(accd[i][j][r] + (double)bias[col]);
                if (ACT == 1) f = fmaxf(f, 0.f);
                if (SPLITOUT == 1) {
                    // exact 2-term fp16 split of f*XS, blocked [row][2K] layout
                    float sv = f * XS;
                    _Float16 p0 = (_Float16)sv;
                    _Float16 p1 = (_Float16)(sv - (float)p0);
                    _Float16* hs = (_Float16*)Cp;
                    size_t base = (size_t)row * (2 * (size_t)N)
                                + (size_t)(col >> 5) * 64 + (col & 31);
                    hs[base]      = p0;
                    hs[base + 32] = p1;
                } else {
                    ((float*)Cp)[(size_t)row * N + col] = f;
                }
            }
}

// ---------------------------------------------------------------------------
// bf16 GEMM with gll16 staging + add-swizzled LDS chunks (decoder).
// XCD-swizzled block mapping. ACT=1: relu->bf16. ACT=2: sigmoid->fp32.
// ---------------------------------------------------------------------------
template <int ACT>
__launch_bounds__(256)
__global__ void gemm_bf16_gll(const __bf16* __restrict__ A, const __bf16* __restrict__ BT,
                              const float* __restrict__ bias, void* __restrict__ Cp,
                              int M, int N, int K)
{
    __shared__ __bf16 Asm[128 * 32];
    __shared__ __bf16 Bsm[128 * 32];

    const int t    = threadIdx.x;
    const int nwg  = gridDim.x * gridDim.y;
    int lin = blockIdx.y * gridDim.x + blockIdx.x;
    lin = (lin & 7) * (nwg >> 3) + (lin >> 3);
    const int bx = lin % gridDim.x, by = lin / gridDim.x;
    const int m0   = by * 128, n0 = bx * 128;
    const int wave = t >> 6, lane = t & 63;
    const int wr   = (wave >> 1) * 64, wc = (wave & 1) * 64;
    const int quad = lane >> 4, l16 = lane & 15;
    const int srow = lane >> 2;
    const int schk = lane & 3;

    floatx4 acc[4][4];
#pragma unroll
    for (int i = 0; i < 4; ++i)
#pragma unroll
        for (int j = 0; j < 4; ++j) acc[i][j] = (floatx4){0.f, 0.f, 0.f, 0.f};

    for (int k0 = 0; k0 < K; k0 += 32) {
        __syncthreads();
#pragma unroll
        for (int s = 0; s < 2; ++s) {
            const int rbase = wave * 32 + s * 16;
            const int ra = rbase + srow;
            const int cs = (schk - (ra >> 1)) & 3;
            gll16((const float*)(A + (size_t)(m0 + ra) * K + k0 + cs * 8),
                  (float*)&Asm[rbase * 32]);
        }
#pragma unroll
        for (int s = 0; s < 2; ++s) {
            const int rbase = wave * 32 + s * 16;
            const int rb = rbase + srow;
            const int cs = (schk - (rb >> 1)) & 3;
            gll16((const float*)(BT + (size_t)(n0 + rb) * K + k0 + cs * 8),
                  (float*)&Bsm[rbase * 32]);
        }
        __syncthreads();

        bf16x8 af[4], bfr[4];
#pragma unroll
        for (int i = 0; i < 4; ++i) {
            const int rl = wr + i * 16 + l16;
            const int sl = (quad + (rl >> 1)) & 3;
            af[i] = *(const bf16x8*)&Asm[rl * 32 + sl * 8];
        }
#pragma unroll
        for (int j = 0; j < 4; ++j) {
            const int rl = wc + j * 16 + l16;
            const int sl = (quad + (rl >> 1)) & 3;
            bfr[j] = *(const bf16x8*)&Bsm[rl * 32 + sl * 8];
        }
#pragma unroll
        for (int i = 0; i < 4; ++i)
#pragma unroll
            for (int j = 0; j < 4; ++j)
                acc[i][j] = __builtin_amdgcn_mfma_f32_16x16x32_bf16(af[i], bfr[j], acc[i][j], 0, 0, 0);
    }

#pragma unroll
    for (int i = 0; i < 4; ++i)
#pragma unroll
        for (int j = 0; j < 4; ++j) {
            int col = n0 + wc + j * 16 + l16;
            float b = bias[col];
#pragma unroll
            for (int r = 0; r < 4; ++r) {
                int row = m0 + wr + i * 16 + quad * 4 + r;
                float v = acc[i][j][r] + b;
                if (ACT == 1) {
                    v = fmaxf(v, 0.f);
                    ((__bf16*)Cp)[(size_t)row * N + col] = (__bf16)v;
                } else {
                    v = 1.f / (1.f + __expf(-v));
                    ((float*)Cp)[(size_t)row * N + col] = v;
                }
            }
        }
}

// x [M][K] fp32 -> xs [M][2K] halves, blocked [ktile][plane][kchunk][8].
__global__ void split_x(const float* __restrict__ in, _Float16* __restrict__ outS, int n8)
{
    int i = blockIdx.x * 256 + threadIdx.x;
    if (i >= n8) return;
    const int K = INDIM;
    int m  = i / (K / 8);
    int k8 = i % (K / 8);
    int k  = k8 * 8;
    const float* src = in + (size_t)m * K + k;
    floatx4 f0 = *(const floatx4*)(src);
    floatx4 f1 = *(const floatx4*)(src + 4);
    union { half8 v; fp16x2 h[4]; } u1, u2;
    float sv[8];
#pragma unroll
    for (int q = 0; q < 4; ++q) sv[q] = f0[q] * XS;
#pragma unroll
    for (int q = 0; q < 4; ++q) sv[4 + q] = f1[q] * XS;
#pragma unroll
    for (int q = 0; q < 4; ++q) {
        fp16x2 hi = __builtin_amdgcn_cvt_pkrtz(sv[2 * q], sv[2 * q + 1]);
        u1.h[q] = hi;
        float r0 = sv[2 * q] - (float)hi[0];
        float r1 = sv[2 * q + 1] - (float)hi[1];
        u2.h[q] = __builtin_amdgcn_cvt_pkrtz(r0, r1);
    }
    size_t base = (size_t)m * (2 * K) + (size_t)(k >> 5) * 64 + (k & 31);
    *(half8*)(outS + base)      = u1.v;     // plane 0
    *(half8*)(outS + base + 32) = u2.v;     // plane 1
}

// W [K][N] fp32 -> [N][2K] halves (same blocked layout), transposed.
__global__ void transpose_split_f16(const float* __restrict__ in, _Float16* __restrict__ outS,
                                    int K, int N)
{
    __shared__ float tile[32][33];
    int k0 = blockIdx.x * 32, n0 = blockIdx.y * 32;
    int tr = threadIdx.x >> 5, tc = threadIdx.x & 31;
#pragma unroll
    for (int s = 0; s < 4; ++s)
        tile[tr + 8 * s][tc] = in[(size_t)(k0 + tr + 8 * s) * N + n0 + tc];
    __syncthreads();
#pragma unroll
    for (int s = 0; s < 4; ++s) {
        int n = n0 + tr + 8 * s;
        int k = k0 + tc;
        float w = tile[tc][tr + 8 * s] * WS;
        _Float16 p0 = (_Float16)w;
        float r = w - (float)p0;
        _Float16 p1 = (_Float16)r;
        size_t base = (size_t)n * (2 * K) + (size_t)(k >> 5) * 64 + (k & 31);
        outS[base]      = p0;
        outS[base + 32] = p1;
    }
}

// ---------------------------------------------------------------------------
// rownorm: nrm[k] = fl32( sum_fp64( fl32(row[k][d]^2) ) ). One wave per row.
// ---------------------------------------------------------------------------
__global__ void rownorm_kernel(const float* __restrict__ M, float* __restrict__ nrm)
{
    int k = blockIdx.x * 4 + (threadIdx.x >> 6);
    int lane = threadIdx.x & 63;
    float2 c = *(const float2*)(M + (size_t)k * DDIM + lane * 2);
    float q0 = c.x * c.x;
    float q1 = c.y * c.y;
    double s = (double)q0 + (double)q1;
#pragma unroll
    for (int off = 32; off > 0; off >>= 1) s += __shfl_down(s, off);
    if (lane == 0) nrm[k] = (float)s;
}

// max over cn32 (one block).
__global__ void cnmax_kernel(const float* __restrict__ cn, float* __restrict__ out)
{
    __shared__ float red[4];
    int t = threadIdx.x;
    float m = 0.f;
    for (int i = t; i < KCB; i += 256) m = fmaxf(m, cn[i]);
#pragma unroll
    for (int off = 32; off > 0; off >>= 1) m = fmaxf(m, __shfl_down(m, off));
    if ((t & 63) == 0) red[t >> 6] = m;
    __syncthreads();
    if (t == 0) out[0] = fmaxf(fmaxf(red[0], red[1]), fmaxf(red[2], red[3]));
}

// fp32 -> fp16 (scaled by exact power of two), 8 elems/thread.
__global__ void cvt_half(const float* __restrict__ in, _Float16* __restrict__ out,
                         float scale, int n8)
{
    int i = blockIdx.x * 256 + threadIdx.x;
    if (i >= n8) return;
    const float4 a = *(const float4*)(in + (size_t)i * 8);
    const float4 b = *(const float4*)(in + (size_t)i * 8 + 4);
    half8 h;
    h[0] = (_Float16)(a.x * scale); h[1] = (_Float16)(a.y * scale);
    h[2] = (_Float16)(a.z * scale); h[3] = (_Float16)(a.w * scale);
    h[4] = (_Float16)(b.x * scale); h[5] = (_Float16)(b.y * scale);
    h[6] = (_Float16)(b.z * scale); h[7] = (_Float16)(b.w * scale);
    *(half8*)(out + (size_t)i * 8) = h;
}

// ---------------------------------------------------------------------------
// N-loop score sweeps (R12 structure + XCD swizzle + cn32 hoist).
// Block = 32 z-rows x ALL 8192 codes (grid 512).
// ---------------------------------------------------------------------------
template <int EMIT>
__launch_bounds__(256)
__global__ void score_sweep2(const _Float16* __restrict__ zh, const _Float16* __restrict__ ch,
                             const float* __restrict__ nz32, const float* __restrict__ cn32,
                             unsigned long long* __restrict__ gbestA,
                             const float* __restrict__ cnmaxp,
                             unsigned* __restrict__ listCnt, unsigned* __restrict__ list)
{
    __shared__ __align__(16) _Float16 Zs[32 * 128];    //  8 KB
    __shared__ __align__(16) _Float16 Cs[128 * 128];   // 32 KB
    __shared__ unsigned long long best[32];            // EMIT==0 combine
    __shared__ unsigned lbuf[LBUF_CAP];                // EMIT==1 candidates
    __shared__ unsigned lcnt, lbase;

    const int t    = threadIdx.x;
    int bid = blockIdx.x;
    bid = (bid & 7) * ((int)gridDim.x >> 3) + (bid >> 3);   // XCD swizzle
    const int m0   = bid * 32;
    const int wave = t >> 6, lane = t & 63;
    const int quad = lane >> 4, l16 = lane & 15;
    const int srow = lane >> 4, sc = lane & 15;

    if (EMIT == 0) { if (t < 32) best[t] = ~0ull; }
    else if (t == 0) lcnt = 0u;

#pragma unroll
    for (int s = 0; s < 2; ++s) {
        const int rbase = s * 16 + wave * 4;
        const int ra = rbase + srow;
        const int cs = sc ^ ((ra & 7) << 1);
        gll16((const float*)(zh + (size_t)(m0 + ra) * 128 + cs * 8),
              (float*)&Zs[rbase * 128]);
    }
    __syncthreads();

    half8 af[2][4];
#pragma unroll
    for (int i = 0; i < 2; ++i) {
        const int rl = i * 16 + l16;
#pragma unroll
        for (int ks = 0; ks < 4; ++ks) {
            const int cc = (ks * 4 + quad) ^ ((rl & 7) << 1);
            af[i][ks] = *(const half8*)&Zs[rl * 128 + cc * 8];
        }
    }

    const float cnm = *cnmaxp;
    float nzv[8], thr[8], bd[8];
    int   bc[8];
#pragma unroll
    for (int i = 0; i < 2; ++i)
#pragma unroll
        for (int r = 0; r < 4; ++r) {
            const int q = i * 4 + r;
            const int grow = m0 + i * 16 + quad * 4 + r;
            nzv[q] = nz32[grow];
            if (EMIT) {
                thr[q] = unpack_d(gbestA[grow]) + 2.4e-3f * sqrtf(nzv[q] * cnm) + 6.0e-5f;
            } else {
                bd[q] = 3.4e38f; bc[q] = 0x7fffffff;
            }
        }

    for (int nt = 0; nt < KCB / 128; ++nt) {
        const int n0 = nt * 128;
        __syncthreads();
#pragma unroll
        for (int s = 0; s < 8; ++s) {
            const int rbase = s * 16 + wave * 4;
            const int ra = rbase + srow;
            const int cs = sc ^ ((ra & 7) << 1);
            gll16((const float*)(ch + (size_t)(n0 + ra) * 128 + cs * 8),
                  (float*)&Cs[rbase * 128]);
        }
        // hoisted cn32 loads (code depends only on j, not (i,r))
        float cnj[2];
#pragma unroll
        for (int j = 0; j < 2; ++j)
            cnj[j] = cn32[n0 + wave * 32 + j * 16 + l16];
        __syncthreads();

        floatx4 acc[2][2];
#pragma unroll
        for (int i = 0; i < 2; ++i)
#pragma unroll
            for (int j = 0; j < 2; ++j) acc[i][j] = (floatx4){0.f, 0.f, 0.f, 0.f};
#pragma unroll
        for (int ks = 0; ks < 4; ++ks) {
            half8 bf[2];
#pragma unroll
            for (int j = 0; j < 2; ++j) {
                const int rl = wave * 32 + j * 16 + l16;
                const int cc = (ks * 4 + quad) ^ ((rl & 7) << 1);
                bf[j] = *(const half8*)&Cs[rl * 128 + cc * 8];
            }
#pragma unroll
            for (int i = 0; i < 2; ++i)
#pragma unroll
                for (int j = 0; j < 2; ++j)
                    acc[i][j] = __builtin_amdgcn_mfma_f32_16x16x32_f16(af[i][ks], bf[j], acc[i][j], 0, 0, 0);
        }

#pragma unroll
        for (int i = 0; i < 2; ++i)
#pragma unroll
            for (int r = 0; r < 4; ++r) {
                const int q = i * 4 + r;
#pragma unroll
                for (int j = 0; j < 2; ++j) {       // codes ascending (tie: first wins)
                    const int code = n0 + wave * 32 + j * 16 + l16;
                    float s = acc[i][j][r] * (1.0f / 4096.0f);
                    float d = (nzv[q] - 2.0f * s) + cnj[j];
                    if (EMIT) {
                        if (d <= thr[q]) {
                            unsigned ent = ((unsigned)(m0 + i * 16 + quad * 4 + r) << 13) | (unsigned)code;
                            unsigned idx = atomicAdd(&lcnt, 1u);
                            if (idx < LBUF_CAP) lbuf[idx] = ent;
                            else {
                                unsigned g = atomicAdd(listCnt, 1u);
                                if (g < CAND_CAP) list[g] = ent;
                            }
                        }
                    } else {
                        if (d < bd[q]) { bd[q] = d; bc[q] = code; }
                    }
                }
            }
    }

    if (EMIT == 0) {
#pragma unroll
        for (int i = 0; i < 2; ++i)
#pragma unroll
            for (int r = 0; r < 4; ++r) {
                const int q = i * 4 + r;
                atomicMin(&best[i * 16 + quad * 4 + r], pack_key(bd[q], bc[q]));
            }
        __syncthreads();
        if (t < 32) gbestA[m0 + t] = best[t];
    } else {
        __syncthreads();
        unsigned cnt = lcnt; if (cnt > LBUF_CAP) cnt = LBUF_CAP;
        if (t == 0) lbase = atomicAdd(listCnt, cnt);
        __syncthreads();
        for (unsigned e = t; e < cnt; e += 256) {
            unsigned g = lbase + e;
            if (g < CAND_CAP) list[g] = lbuf[e];
        }
    }
}

// Exact refine: one wave per candidate pair.
__launch_bounds__(256)
__global__ void refine_kernel(const float* __restrict__ z, const float* __restrict__ cb,
                              const float* __restrict__ nz32, const float* __restrict__ cn32,
                              const unsigned* __restrict__ listCnt,
                              const unsigned* __restrict__ list,
                              unsigned long long* __restrict__ gbest)
{
    unsigned cnt = *listCnt;
    if (cnt > CAND_CAP) cnt = CAND_CAP;
    const int lane = threadIdx.x & 63;
    for (unsigned p = blockIdx.x * 4 + (threadIdx.x >> 6); p < cnt; p += gridDim.x * 4) {
        const unsigned e = list[p];
        const int r = (int)(e >> 13), k = (int)(e & 8191u);
        float2 zv = *(const float2*)(z  + (size_t)r * DDIM + lane * 2);
        float2 cv = *(const float2*)(cb + (size_t)k * DDIM + lane * 2);
        double s = (double)zv.x * (double)cv.x + (double)zv.y * (double)cv.y;
#pragma unroll
        for (int off = 32; off > 0; off >>= 1) s += __shfl_down(s, off);
        if (lane == 0) {
            float s32 = (float)s;
            float d = (nz32[r] - 2.0f * s32) + cn32[k];
            atomicMin(&gbest[r], pack_key(d, k));
        }
    }
}

// init gbest (all blocks) + scalars (block 0).
__global__ void init_gbest(unsigned long long* __restrict__ g,
                           double* __restrict__ acc, unsigned* __restrict__ cnt)
{
    g[blockIdx.x * 256 + threadIdx.x] = ~0ull;
    if (blockIdx.x == 0 && threadIdx.x == 0) { *acc = 0.0; *cnt = 0u; }
}

// Gather z_q = codebook[idx] as bf16 (zqb) + accumulate sum((z_q - z)^2) f64.
__global__ void gather_zq_loss(const float* __restrict__ z, const float* __restrict__ cb,
                               const unsigned long long* __restrict__ gbest,
                               __bf16* __restrict__ zqb, double* __restrict__ acc)
{
    int r = blockIdx.x * 4 + (threadIdx.x >> 6);
    int lane = threadIdx.x & 63;
    int k = (int)(gbest[r] & 0xffffffffull);
    float2 zv = *(const float2*)(z  + (size_t)r * DDIM + lane * 2);
    float2 cv = *(const float2*)(cb + (size_t)k * DDIM + lane * 2);
    __bf16 b0 = (__bf16)cv.x, b1 = (__bf16)cv.y;
    zqb[(size_t)r * DDIM + lane * 2]     = b0;
    zqb[(size_t)r * DDIM + lane * 2 + 1] = b1;
    double dx = (double)cv.x - (double)zv.x, dy = (double)cv.y - (double)zv.y;
    double s = dx * dx + dy * dy;
#pragma unroll
    for (int off = 32; off > 0; off >>= 1) s += __shfl_down(s, off);
    if (lane == 0) atomicAdd(acc, s);
}

__global__ void finalize_kernel(const unsigned long long* __restrict__ gbest,
                                const double* __restrict__ acc, float* __restrict__ out)
{
    int tid = blockIdx.x * 256 + threadIdx.x;
    if (tid < B_) out[16777217 + tid] = (float)(int)(gbest[tid] & 0xffffffffull);
    if (tid == 0) out[16777216] = (float)((*acc) * 1.25 / (double)(B_ * DDIM));
}

// ---------------------------------------------------------------------------
// One-time weight transposes: fp32 [K][N] -> bf16 [N][K].
// ---------------------------------------------------------------------------
__global__ void transpose_to_bf16(const float* __restrict__ in, __bf16* __restrict__ outT,
                                  int K, int N)
{
    __shared__ float tile[32][33];
    int k0 = blockIdx.x * 32, n0 = blockIdx.y * 32;
    int tr = threadIdx.x >> 5, tc = threadIdx.x & 31;
#pragma unroll
    for (int s = 0; s < 4; ++s)
        tile[tr + 8 * s][tc] = in[(size_t)(k0 + tr + 8 * s) * N + n0 + tc];
    __syncthreads();
#pragma unroll
    for (int s = 0; s < 4; ++s)
        outT[(size_t)(n0 + tr + 8 * s) * K + k0 + tc] = (__bf16)tile[tc][tr + 8 * s];
}

// ---------------------------------------------------------------------------
extern "C" void kernel_launch(void* const* d_in, const int* in_sizes, int n_in,
                              void* d_out, int out_size, void* d_ws, size_t ws_size,
                              hipStream_t stream)
{
    const float* x  = (const float*)d_in[0];
    const float* W1 = (const float*)d_in[1];
    const float* b1 = (const float*)d_in[2];
    const float* W2 = (const float*)d_in[3];
    const float* b2 = (const float*)d_in[4];
    const float* cb = (const float*)d_in[5];
    const float* W3 = (const float*)d_in[6];
    const float* b3 = (const float*)d_in[7];
    const float* W4 = (const float*)d_in[8];
    const float* b4 = (const float*)d_in[9];
    float* out = (float*)d_out;

    char* ws = (char*)d_ws;
    // Memory map (pre-split path). NOTE: hs is 128MB ([16384][2*2048] fp16).
    //   [0,128MB)   hs split-h, live G1->G2 (fallback: h fp32 [0,128MB))
    //   [0,4MB)     zh  fp16 z   (post-G2, hs dead)    \
    //   [4,6MB)     chh fp16 cb  (post-G2)              } dead-hs region
    //   [6,8MB)     gbestA       (post-G2)              }
    //   [8,16MB)    cand list    (post-G2)             /
    //   [16,80MB)   h2b decoder bf16 (written by G3, after sweeps)
    //   [128MB..)   z32, zqb/W1s, nz32, cn32, gbest, acc, W3t, W4t, W2s
    //   [150MB..)   xs pre-split x (64MB, dead after G1)
    _Float16* hs = (_Float16*)(ws);                   // 128 MB [16384][2*2048]
    float*  h    = (float*)(ws);                      // fallback fp32
    __bf16* h2b  = (__bf16*)(ws + 16777216ull);       // 64 MB
    _Float16* zh  = (_Float16*)(ws);                  //  4 MB (dead-hs, post-G2)
    _Float16* chh = (_Float16*)(ws + 4194304ull);     //  2 MB (dead-hs, post-G2)
    unsigned long long* gbestA = (unsigned long long*)(ws + 6291456ull);
    unsigned* list = (unsigned*)(ws + 8388608ull);    //  8 MB
    float*  z32  = (float*)(ws + 134217728ull);       //  8 MB
    __bf16* zqb  = (__bf16*)(ws + 142606336ull);      //  4 MB
    _Float16* W1s = (_Float16*)(ws + 142606336ull);   //  8 MB (alias of zqb; dead before gather)
    float*  nz32 = (float*)(ws + 150994944ull);       // 64 KB
    float*  cn32 = (float*)(ws + 151060480ull);       // 32 KB
    unsigned long long* gbest = (unsigned long long*)(ws + 151093248ull); // 128 KB
    double* acc  = (double*)(ws + 151224320ull);      // 8 B (4KB pad)
    float*  cnmax   = (float*)(ws + 151224328ull);    // 4 B
    unsigned* listCnt = (unsigned*)(ws + 151224332ull); // 4 B
    __bf16* W3t  = (__bf16*)(ws + 151228416ull);      // 512 KB [2048][128]
    __bf16* W4t  = (__bf16*)(ws + 151752704ull);      //   4 MB [1024][2048]
    _Float16* W2s = (_Float16*)(ws + 155947008ull);   //   1 MB [128][2*2048]

    const unsigned long long XS_OFF = 157286400ull;   // 150 MB
    _Float16* xs = (_Float16*)(ws + XS_OFF);
    const bool pre_split_x = (ws_size >= XS_OFF + 67108864ull);

    init_gbest<<<B_ / 256, 256, 0, stream>>>(gbest, acc, listCnt);
    rownorm_kernel<<<KCB / 4, 256, 0, stream>>>(cb, cn32);
    cnmax_kernel<<<1, 256, 0, stream>>>(cn32, cnmax);
    transpose_to_bf16<<<dim3(DDIM / 32, HID / 32), 256, 0, stream>>>(W3, W3t, DDIM, HID);
    transpose_to_bf16<<<dim3(HID / 32, INDIM / 32), 256, 0, stream>>>(W4, W4t, HID, INDIM);
    transpose_split_f16<<<dim3(INDIM / 32, HID / 32), 256, 0, stream>>>(W1, W1s, INDIM, HID);
    transpose_split_f16<<<dim3(HID / 32, DDIM / 32), 256, 0, stream>>>(W2, W2s, HID, DDIM);

    if (pre_split_x) {
        // h(split) = relu(x@W1 + b1): pre-split GEMM, split-store epilogue
        split_x<<<(B_ * INDIM / 8) / 256, 256, 0, stream>>>(x, xs, B_ * INDIM / 8);
        gemm_split_pre<4, 1, 3, 1><<<dim3(HID / 64, B_ / 128), 256, 0, stream>>>(
            xs, W1s, b1, (void*)hs, B_, HID, INDIM);
        // z32 = h@W2 + b2: pure pre-split GEMM, BM=64 (grid 512 = 2/CU)
        gemm_split_pre<2, 0, 1, 0><<<dim3(DDIM / 64, B_ / 64), 256, 0, stream>>>(
            hs, W2s, b2, (void*)z32, B_, DDIM, HID);
    } else {
        gemm_split_f16<1, 3><<<dim3(HID / 64, B_ / 128), 256, 0, stream>>>(
            x, W1s, b1, h, B_, HID, INDIM);
        gemm_split_f16<0, 1><<<dim3(DDIM / 64, B_ / 128), 256, 0, stream>>>(
            h, W2s, b2, z32, B_, DDIM, HID);
    }
    // nz32 = fl32(sum fl32(z^2))
    rownorm_kernel<<<B_ / 4, 256, 0, stream>>>(z32, nz32);

    // --- fast score path: fp16 views (post-G2, hs dead) + N-loop sweeps ---
    cvt_half<<<(B_ * DDIM / 8) / 256, 256, 0, stream>>>(z32, zh, 1.0f, B_ * DDIM / 8);
    cvt_half<<<(KCB * DDIM / 8) / 256, 256, 0, stream>>>(cb, chh, 4096.0f, KCB * DDIM / 8);
    score_sweep2<0><<<B_ / 32, 256, 0, stream>>>(
        zh, chh, nz32, cn32, gbestA, cnmax, listCnt, list);
    score_sweep2<1><<<B_ / 32, 256, 0, stream>>>(
        zh, chh, nz32, cn32, gbestA, cnmax, listCnt, list);
    refine_kernel<<<1024, 256, 0, stream>>>(z32, cb, nz32, cn32, listCnt, list, gbest);

    // z_q gather (bf16) + commitment loss
    gather_zq_loss<<<B_ / 4, 256, 0, stream>>>(z32, cb, gbest, zqb, acc);
    // h2 = relu(zqb@W3 + b3) -> bf16              [16384,128]x[128,2048]
    gemm_bf16_gll<1><<<dim3(HID / 128, B_ / 128), 256, 0, stream>>>(
        zqb, W3t, b3, (void*)h2b, B_, HID, DDIM);
    // recon = sigmoid(h2@W4 + b4) -> fp32 out     [16384,2048]x[2048,1024]
    gemm_bf16_gll<2><<<dim3(INDIM / 128, B_ / 128), 256, 0, stream>>>(
        h2b, W4t, b4, (void*)out, B_, INDIM, HID);

    finalize_kernel<<<B_ / 256, 256, 0, stream>>>(gbest, acc, out);
}